// Round 1
// baseline (435.846 us; speedup 1.0000x reference)
//
#include <hip/hip_runtime.h>

// ---- problem constants (must match reference exactly) ----
constexpr int GX = 1408, GY = 1600, GZ = 40;
constexpr float LOX = 0.0f, LOY = -40.0f, LOZ = -3.0f;
constexpr float VSX = 0.05f, VSY = 0.05f, VSZ = 0.1f;
constexpr int MAXV = 60000, MAXP = 35;
constexpr int HASH_BITS = 22;
constexpr int H = 1 << HASH_BITS;           // 4,194,304 slots, load ~45%

// output layout (floats)
constexpr size_t VOX_OFF = 0;                              // 60000*35*4
constexpr size_t CO_OFF  = (size_t)MAXV * MAXP * 4;        // 8,400,000
constexpr size_t NP_OFF  = CO_OFF + (size_t)MAXV * 3;      // 8,580,000
constexpr size_t VN_OFF  = NP_OFF + (size_t)MAXV;          // 8,640,000

// ---------------- kernel 1: hash-insert all points ----------------
__global__ __launch_bounds__(256) void k_hash(const float4* __restrict__ pts, int n,
                                              int* __restrict__ keys,
                                              int* __restrict__ first,
                                              int* __restrict__ pslot) {
    int i = blockIdx.x * 256 + threadIdx.x;
    if (i >= n) return;
    float4 p = pts[i];
    float fx = floorf((p.x - LOX) / VSX);
    float fy = floorf((p.y - LOY) / VSY);
    float fz = floorf((p.z - LOZ) / VSZ);
    if (fx < 0.f || fy < 0.f || fz < 0.f ||
        fx >= (float)GX || fy >= (float)GY || fz >= (float)GZ) {
        pslot[i] = -1;
        return;
    }
    int xi = (int)fx, yi = (int)fy, zi = (int)fz;
    int lin = (zi * GY + yi) * GX + xi;
    unsigned h = ((unsigned)lin * 2654435761u) >> (32 - HASH_BITS);
    while (true) {
        int k = keys[h];                     // keys only transition -1 -> final
        if (k == lin) break;
        if (k == -1) {
            int old = atomicCAS(&keys[h], -1, lin);
            if (old == -1 || old == lin) break;
        }
        h = (h + 1) & (H - 1);
    }
    pslot[i] = (int)h;
    atomicMin(&first[h], i);
}

// ---------------- kernel 2: per-block leader counts ----------------
__global__ __launch_bounds__(256) void k_bsum(const int* __restrict__ first,
                                              const int* __restrict__ pslot,
                                              int n, int* __restrict__ bsums) {
    int i = blockIdx.x * 256 + threadIdx.x;
    int flag = 0;
    if (i < n) {
        int s = pslot[i];
        if (s >= 0 && first[s] == i) flag = 1;
    }
    unsigned long long b = __ballot(flag);
    __shared__ int wsum[4];
    int lane = threadIdx.x & 63, wid = threadIdx.x >> 6;
    if (lane == 0) wsum[wid] = __popcll(b);
    __syncthreads();
    if (threadIdx.x == 0)
        bsums[blockIdx.x] = wsum[0] + wsum[1] + wsum[2] + wsum[3];
}

// ---------------- kernel 3: scan block sums (in place, exclusive) ----------------
__global__ __launch_bounds__(256) void k_scan(int* __restrict__ bsums, int nb,
                                              float* __restrict__ vn_out) {
    __shared__ int sh[256];
    __shared__ int carry;
    if (threadIdx.x == 0) carry = 0;
    __syncthreads();
    for (int base = 0; base < nb; base += 256) {
        int idx = base + threadIdx.x;
        int v = (idx < nb) ? bsums[idx] : 0;
        sh[threadIdx.x] = v;
        __syncthreads();
        for (int off = 1; off < 256; off <<= 1) {
            int t = (threadIdx.x >= off) ? sh[threadIdx.x - off] : 0;
            __syncthreads();
            sh[threadIdx.x] += t;
            __syncthreads();
        }
        int incl = sh[threadIdx.x];
        int excl = incl - v + carry;          // reads carry from prev iter
        if (idx < nb) bsums[idx] = excl;
        __syncthreads();
        if (threadIdx.x == 255) carry += incl;
        __syncthreads();
    }
    if (threadIdx.x == 0) vn_out[0] = (float)min(carry, MAXV);
}

// ---------------- kernel 4: assign vids, write coors ----------------
__global__ __launch_bounds__(256) void k_assign(const int* __restrict__ first,
                                                const int* __restrict__ pslot,
                                                int* __restrict__ keys,   // repurposed -> vids
                                                const int* __restrict__ boffs,
                                                int n, float* __restrict__ coors_out) {
    int i = blockIdx.x * 256 + threadIdx.x;
    int flag = 0, s = -1;
    if (i < n) {
        s = pslot[i];
        if (s >= 0 && first[s] == i) flag = 1;
    }
    unsigned long long b = __ballot(flag);
    int lane = threadIdx.x & 63, wid = threadIdx.x >> 6;
    __shared__ int wsum[4];
    if (lane == 0) wsum[wid] = __popcll(b);
    __syncthreads();
    int waveoff = 0;
    for (int w = 0; w < wid; ++w) waveoff += wsum[w];
    int intra = waveoff + __popcll(b & ((1ull << lane) - 1));
    if (flag) {
        int vid = boffs[blockIdx.x] + intra;
        int lin = keys[s];
        keys[s] = vid;                        // slot now holds vid (only leader touches it)
        if (vid < MAXV) {
            int x = lin % GX;
            int t = lin / GX;
            int y = t % GY;
            int z = t / GY;
            coors_out[(size_t)vid * 3 + 0] = (float)z;
            coors_out[(size_t)vid * 3 + 1] = (float)y;
            coors_out[(size_t)vid * 3 + 2] = (float)x;
        }
    }
}

// ---------------- kernel 5: append point indices to kept voxels ----------------
__global__ __launch_bounds__(256) void k_fill(const int* __restrict__ pslot,
                                              const int* __restrict__ vids,
                                              int* __restrict__ cursor,
                                              int* __restrict__ lists, int n) {
    int i = blockIdx.x * 256 + threadIdx.x;
    if (i >= n) return;
    int s = pslot[i];
    if (s < 0) return;
    int v = vids[s];
    if (v >= MAXV) return;
    int j = atomicAdd(&cursor[v], 1);
    if (j < MAXP) lists[v * MAXP + j] = i;
}

// ---------------- kernel 6: sort per-voxel indices, write voxels/numpv ----------------
__global__ __launch_bounds__(256) void k_write(const int* __restrict__ cursor,
                                               const int* __restrict__ lists,
                                               const float4* __restrict__ pts,
                                               float* __restrict__ vox_out,
                                               float* __restrict__ np_out) {
    int v = blockIdx.x * 256 + threadIdx.x;
    if (v >= MAXV) return;
    int c = cursor[v];
    if (c == 0) return;
    int k = min(c, MAXP);
    int idx[MAXP];
    for (int r = 0; r < k; ++r) idx[r] = lists[v * MAXP + r];
    // insertion sort ascending (restores original arrival order)
    for (int a = 1; a < k; ++a) {
        int key = idx[a];
        int b = a - 1;
        while (b >= 0 && idx[b] > key) { idx[b + 1] = idx[b]; --b; }
        idx[b + 1] = key;
    }
    for (int r = 0; r < k; ++r) {
        float4 p = pts[idx[r]];
        ((float4*)vox_out)[(size_t)v * MAXP + r] = p;
    }
    np_out[v] = (float)k;
}

extern "C" void kernel_launch(void* const* d_in, const int* in_sizes, int n_in,
                              void* d_out, int out_size, void* d_ws, size_t ws_size,
                              hipStream_t stream) {
    const float4* pts = (const float4*)d_in[0];
    int n = in_sizes[0] / 4;
    float* out = (float*)d_out;
    char* ws = (char*)d_ws;

    // workspace layout (bytes)
    int* keys   = (int*)(ws);                               // 16 MB (repurposed as vids)
    int* first  = (int*)(ws + (size_t)H * 4);               // 16 MB
    int* pslot  = (int*)(ws + (size_t)H * 8);               // 8 MB
    size_t off  = (size_t)H * 8 + (size_t)n * 4;
    off = (off + 255) & ~(size_t)255;
    int* bsums  = (int*)(ws + off);                         // ~32 KB
    off += 65536;
    int* cursor = (int*)(ws + off);                         // 240 KB
    off += (size_t)MAXV * 4;
    int* lists  = (int*)(ws + off);                         // 8.4 MB

    hipMemsetAsync(keys, 0xFF, (size_t)H * 4, stream);          // -1
    hipMemsetAsync(first, 0x7F, (size_t)H * 4, stream);         // 0x7F7F7F7F (> any index)
    hipMemsetAsync(cursor, 0, (size_t)MAXV * 4, stream);
    hipMemsetAsync(out, 0, (size_t)out_size * 4, stream);

    int nb = (n + 255) / 256;
    k_hash<<<nb, 256, 0, stream>>>(pts, n, keys, first, pslot);
    k_bsum<<<nb, 256, 0, stream>>>(first, pslot, n, bsums);
    k_scan<<<1, 256, 0, stream>>>(bsums, nb, out + VN_OFF);
    k_assign<<<nb, 256, 0, stream>>>(first, pslot, keys, bsums, n, out + CO_OFF);
    k_fill<<<nb, 256, 0, stream>>>(pslot, keys, cursor, lists, n);
    k_write<<<(MAXV + 255) / 256, 256, 0, stream>>>(cursor, lists, pts, out, out + NP_OFF);
}

// Round 2
// 355.212 us; speedup vs baseline: 1.2270x; 1.2270x over previous
//
#include <hip/hip_runtime.h>

// ---- problem constants (must match reference exactly) ----
constexpr int GX = 1408, GY = 1600, GZ = 40;
constexpr float LOX = 0.0f, LOY = -40.0f, LOZ = -3.0f;
constexpr float VSX = 0.05f, VSY = 0.05f, VSZ = 0.1f;
constexpr int MAXV = 60000, MAXP = 35;
constexpr int HASH_BITS = 22;
constexpr int H = 1 << HASH_BITS;              // 4,194,304 slots x 8B = 32 MB
constexpr int LINBITS = 27;                    // grid has 90,112,000 < 2^27 cells
constexpr unsigned LINMASK = (1u << LINBITS) - 1;
constexpr unsigned long long EMPTY = ~0ULL;
constexpr int LEADER_BIT = 1 << 30;            // stored in pslot (slot ids < 2^22)

// output layout (floats)
constexpr size_t VOX_OFF = 0;                              // 60000*35*4
constexpr size_t CO_OFF  = (size_t)MAXV * MAXP * 4;        // 8,400,000
constexpr size_t NP_OFF  = CO_OFF + (size_t)MAXV * 3;      // 8,580,000
constexpr size_t VN_OFF  = NP_OFF + (size_t)MAXV;          // 8,640,000

__device__ __forceinline__ unsigned hashlin(unsigned lin) {
    return (lin * 2654435761u) >> (32 - HASH_BITS);
}

// ---------------- kernel 1: hash-insert all points (single packed table) ----------------
__global__ __launch_bounds__(256) void k_hash(const float4* __restrict__ pts, int n,
                                              unsigned long long* __restrict__ table,
                                              int* __restrict__ pslot) {
    int i = blockIdx.x * 256 + threadIdx.x;
    if (i >= n) return;
    float4 p = pts[i];
    float fx = floorf((p.x - LOX) / VSX);
    float fy = floorf((p.y - LOY) / VSY);
    float fz = floorf((p.z - LOZ) / VSZ);
    if (fx < 0.f || fy < 0.f || fz < 0.f ||
        fx >= (float)GX || fy >= (float)GY || fz >= (float)GZ) {
        pslot[i] = -1;
        return;
    }
    unsigned lin = ((unsigned)(int)fz * GY + (unsigned)(int)fy) * GX + (unsigned)(int)fx;
    unsigned long long my = ((unsigned long long)(unsigned)i << LINBITS) | lin;
    unsigned h = hashlin(lin);
    while (true) {
        unsigned long long cur = table[h];
        if (cur == EMPTY) {
            unsigned long long old = atomicCAS(&table[h], EMPTY, my);
            if (old == EMPTY) break;            // inserted, we are current min
            cur = old;
        }
        if ((unsigned)(cur & LINMASK) == lin) { // our voxel's slot
            atomicMin(&table[h], my);
            break;
        }
        h = (h + 1) & (H - 1);
    }
    pslot[i] = (int)h;
}

// ---------------- kernel 2: leader detect (one gather) + per-block counts ----------------
__global__ __launch_bounds__(256) void k_bsum(const unsigned long long* __restrict__ table,
                                              int* __restrict__ pslot,
                                              int n, int* __restrict__ bsums) {
    int i = blockIdx.x * 256 + threadIdx.x;
    int flag = 0, p = -1;
    if (i < n) {
        p = pslot[i];
        if (p >= 0) {
            unsigned long long v = table[p];
            if ((unsigned)(v >> LINBITS) == (unsigned)i) flag = 1;
        }
    }
    unsigned long long b = __ballot(flag);
    __shared__ int wsum[4];
    int lane = threadIdx.x & 63, wid = threadIdx.x >> 6;
    if (lane == 0) wsum[wid] = __popcll(b);
    __syncthreads();
    if (threadIdx.x == 0)
        bsums[blockIdx.x] = wsum[0] + wsum[1] + wsum[2] + wsum[3];
    if (flag) pslot[i] = p | LEADER_BIT;       // coalesced flag write, no re-gather later
}

// ---------------- kernel 3: scan block sums (in place, exclusive) ----------------
__global__ __launch_bounds__(256) void k_scan(int* __restrict__ bsums, int nb,
                                              float* __restrict__ vn_out) {
    __shared__ int sh[256];
    __shared__ int carry;
    if (threadIdx.x == 0) carry = 0;
    __syncthreads();
    for (int base = 0; base < nb; base += 256) {
        int idx = base + threadIdx.x;
        int v = (idx < nb) ? bsums[idx] : 0;
        sh[threadIdx.x] = v;
        __syncthreads();
        for (int off = 1; off < 256; off <<= 1) {
            int t = (threadIdx.x >= off) ? sh[threadIdx.x - off] : 0;
            __syncthreads();
            sh[threadIdx.x] += t;
            __syncthreads();
        }
        int incl = sh[threadIdx.x];
        int excl = incl - v + carry;
        if (idx < nb) bsums[idx] = excl;
        __syncthreads();
        if (threadIdx.x == 255) carry += incl;
        __syncthreads();
    }
    if (threadIdx.x == 0) vn_out[0] = (float)min(carry, MAXV);
}

// ---------------- kernel 4: leaders assign vids (slot RMW), write coors ----------------
__global__ __launch_bounds__(256) void k_assign(unsigned long long* __restrict__ table,
                                                const int* __restrict__ pslot,
                                                const int* __restrict__ boffs,
                                                int n, float* __restrict__ coors_out) {
    int i = blockIdx.x * 256 + threadIdx.x;
    int p = (i < n) ? pslot[i] : -1;
    int flag = (p != -1) && (p & LEADER_BIT);
    unsigned long long b = __ballot(flag);
    int lane = threadIdx.x & 63, wid = threadIdx.x >> 6;
    __shared__ int wsum[4];
    if (lane == 0) wsum[wid] = __popcll(b);
    __syncthreads();
    int waveoff = 0;
    for (int w = 0; w < wid; ++w) waveoff += wsum[w];
    int intra = waveoff + __popcll(b & ((1ull << lane) - 1));
    if (flag) {
        int vid = boffs[blockIdx.x] + intra;
        int s = p & (H - 1);
        unsigned long long v = table[s];       // fetch line we're about to write anyway
        table[s] = (unsigned long long)(unsigned)vid;  // slot now holds vid
        if (vid < MAXV) {
            unsigned lin = (unsigned)(v & LINMASK);
            int x = (int)(lin % (unsigned)GX);
            unsigned t = lin / (unsigned)GX;
            int y = (int)(t % (unsigned)GY);
            int z = (int)(t / (unsigned)GY);
            coors_out[(size_t)vid * 3 + 0] = (float)z;
            coors_out[(size_t)vid * 3 + 1] = (float)y;
            coors_out[(size_t)vid * 3 + 2] = (float)x;
        }
    }
}

// ---------------- kernel 5: append point indices to kept voxels (one gather) ----------------
__global__ __launch_bounds__(256) void k_fill(const unsigned long long* __restrict__ table,
                                              const int* __restrict__ pslot,
                                              int* __restrict__ cursor,
                                              int* __restrict__ lists, int n) {
    int i = blockIdx.x * 256 + threadIdx.x;
    if (i >= n) return;
    int p = pslot[i];
    if (p == -1) return;
    int s = p & (H - 1);
    unsigned vid = (unsigned)table[s];
    if (vid >= (unsigned)MAXV) return;
    int j = atomicAdd(&cursor[vid], 1);
    if (j < MAXP) lists[vid * MAXP + j] = i;
}

// ---------------- kernel 6: sort per-voxel indices, write voxels/numpv ----------------
__global__ __launch_bounds__(256) void k_write(const int* __restrict__ cursor,
                                               const int* __restrict__ lists,
                                               const float4* __restrict__ pts,
                                               float* __restrict__ vox_out,
                                               float* __restrict__ np_out) {
    int v = blockIdx.x * 256 + threadIdx.x;
    if (v >= MAXV) return;
    int c = cursor[v];
    if (c == 0) return;
    int k = min(c, MAXP);
    int idx[MAXP];
    for (int r = 0; r < k; ++r) idx[r] = lists[v * MAXP + r];
    for (int a = 1; a < k; ++a) {              // insertion sort: restore arrival order
        int key = idx[a];
        int b = a - 1;
        while (b >= 0 && idx[b] > key) { idx[b + 1] = idx[b]; --b; }
        idx[b + 1] = key;
    }
    for (int r = 0; r < k; ++r) {
        float4 p = pts[idx[r]];
        ((float4*)vox_out)[(size_t)v * MAXP + r] = p;
    }
    np_out[v] = (float)k;
}

extern "C" void kernel_launch(void* const* d_in, const int* in_sizes, int n_in,
                              void* d_out, int out_size, void* d_ws, size_t ws_size,
                              hipStream_t stream) {
    const float4* pts = (const float4*)d_in[0];
    int n = in_sizes[0] / 4;
    float* out = (float*)d_out;
    char* ws = (char*)d_ws;

    // workspace layout (bytes)
    unsigned long long* table = (unsigned long long*)(ws);        // 32 MB
    int* pslot = (int*)(ws + (size_t)H * 8);                      // 8 MB
    size_t off = (size_t)H * 8 + (size_t)n * 4;
    off = (off + 255) & ~(size_t)255;
    int* bsums  = (int*)(ws + off);                               // ~32 KB
    off += 65536;
    int* cursor = (int*)(ws + off);                               // 240 KB
    off += (size_t)MAXV * 4;
    int* lists  = (int*)(ws + off);                               // 8.4 MB

    hipMemsetAsync(table, 0xFF, (size_t)H * 8, stream);           // EMPTY
    hipMemsetAsync(cursor, 0, (size_t)MAXV * 4, stream);
    hipMemsetAsync(out, 0, (size_t)out_size * 4, stream);

    int nb = (n + 255) / 256;
    k_hash<<<nb, 256, 0, stream>>>(pts, n, table, pslot);
    k_bsum<<<nb, 256, 0, stream>>>(table, pslot, n, bsums);
    k_scan<<<1, 256, 0, stream>>>(bsums, nb, out + VN_OFF);
    k_assign<<<nb, 256, 0, stream>>>(table, pslot, bsums, n, out + CO_OFF);
    k_fill<<<nb, 256, 0, stream>>>(table, pslot, cursor, lists, n);
    k_write<<<(MAXV + 255) / 256, 256, 0, stream>>>(cursor, lists, pts, out, out + NP_OFF);
}